// Round 3
// baseline (29066.495 us; speedup 1.0000x reference)
//
#include <hip/hip_runtime.h>
#include <stdint.h>

#define T_STEPS 4096
#define BATCH 32
#define HID 512
#define GROUPS 8            // blocks per batch
#define BLK_THREADS 1024    // 16 waves; 256 blocks = exactly 1/CU
#define NBLOCKS 256
#define BSLOT_DW 256                 // dwords per (slot,batch) h record: 8 groups x 32
#define SLOT_DW (BATCH * BSLOT_DW)   // dwords per parity slot (8192 = 32 KB)

typedef _Float16 h2_t __attribute__((ext_vector_type(2)));
typedef uint32_t u32x4 __attribute__((ext_vector_type(4)));

__device__ inline uint32_t pack_h2(float a, float b) {
  h2_t v;
  v.x = (_Float16)a;
  v.y = (_Float16)b;
  return __builtin_bit_cast(uint32_t, v);
}

__device__ inline float fdot2(uint32_t a, uint32_t b, float c) {
  return __builtin_amdgcn_fdot2(__builtin_bit_cast(h2_t, a),
                                __builtin_bit_cast(h2_t, b), c, false);
}

__device__ inline float sigf(float x) { return 1.0f / (1.0f + __expf(-x)); }
__device__ inline float tanh_fast(float x) {
  float a = fabsf(x);
  float e = __expf(-2.0f * a);
  float r = (1.0f - e) / (1.0f + e);
  return copysignf(r, x);
}

// Round 12: vector-path agent-scope communication, single-poller design.
//
// Round-11 post-mortem: fusing the scalar loads bought only 3% -> the
// bottleneck was never the RT count; it was 16 waves/block spamming
// {s_dcache_inv + 8 s_loads} through ONE scalar unit and a small-MSHR K$
// (up to 128 concurrent scalar misses serialize at ~1 RT each).
//
// New protocol (all through the XCD's L2, same-XCD guaranteed by the claim):
//   producer (wave 0):  32 coalesced data stores -> s_waitcnt vmcnt(0) ->
//                       __hip_atomic_store(tag=t+1, RELEASE, AGENT)
//   poller  (wave 15):  8 lanes poll tags[b][0..7] with relaxed AGENT loads
//                       (sc1 = the cache-scope bit round-6/7's sc0 attempt
//                       was missing); when all >= t, 64 lanes fetch the
//                       whole 1 KB batch record (2 qword AGENT loads/lane,
//                       one parallel RT) and write it to LDS.
//   everyone else:      waits at __syncthreads() (barrier #1), then reads h
//                       by broadcast ds_read_b128 (conflict-free).
// Tags are monotonic (poll >= t), data slots parity-buffered; overwrite
// safety identical to rounds 9-11: publishing t+2 into slot[t&1] requires
// passing the t+1 barrier, which transitively requires every consumer to
// have consumed slot[t&1] at step t. Issue-after-check ordering on the
// consumer + release on the producer makes data reads fresh (both sides hit
// the same L2 with agent-scope ops).
__global__ __launch_bounds__(BLK_THREADS)
void lstm_vecagent(const float* __restrict__ x0,
                   const float* __restrict__ W_ih,
                   const float* __restrict__ W_hh,
                   const float* __restrict__ b_ih,
                   const float* __restrict__ b_hh,
                   const float* __restrict__ W_lin,
                   const float* __restrict__ b_lin,
                   float* __restrict__ y,
                   uint32_t* __restrict__ h_ex,   // [2][BATCH][GROUPS][32]
                   uint32_t* __restrict__ tags,   // [BATCH][8] monotonic
                   int* __restrict__ claim)       // [8][16] per-XCD claim
{
  __shared__ float x0_lds[T_STEPS];     // 16 KB: this batch's x0 column
  __shared__ float ylds[T_STEPS];       // 16 KB: per-block y partials
  __shared__ float gacc[2][256];        // parity-buffered gate accumulators
  __shared__ __align__(16) uint32_t h_lds[2][BSLOT_DW];  // 2 KB: h broadcast
  __shared__ int s_bg;

  const int tid = threadIdx.x;

  // ---- claim a (batch, group) slot on THIS block's physical XCD ----
  if (tid == 0) {
    uint32_t xcc;
    asm volatile("s_getreg_b32 %0, hwreg(HW_REG_XCC_ID)" : "=s"(xcc));
    xcc &= 7;
    int slot = atomicAdd(claim + xcc * 16, 1);   // agent-scope, one-time
    s_bg = (slot < 32) ? (int)(((4 * xcc + (slot >> 3)) << 3) | (slot & 7))
                       : -1;
  }
  __syncthreads();
  if (s_bg < 0) return;                  // surplus block
  const int b  = s_bg >> 3;              // batch (same XCD for all 8 groups)
  const int g  = s_bg & 7;               // group within batch
  const int u0 = g * 64;                 // first hidden unit owned
  const int wv = tid >> 6;               // wave 0..15
  const int rg = wv >> 3;                // row-group 0..1
  const int cs = wv & 7;                 // col-slice 0..7 == producer group
  const int l  = tid & 63;

  // ---- one-time: W_hh slice -> packed f16x2 -> VGPRs (no AGPR round-trip:
  // removes 64 v_accvgpr_read per wave per step; total regs must stay <=128
  // so the 16-wave block still fits the CU) ----
  uint32_t w0[32], w1[32];
  {
    const int r0 = 128 * rg + l;
    const int r1 = r0 + 64;
    const int R0 = (r0 >> 6) * HID + u0 + (r0 & 63);  // gate*512 + unit
    const int R1 = (r1 >> 6) * HID + u0 + (r1 & 63);
    const float2* p0 = (const float2*)(W_hh + (size_t)R0 * HID + 64 * cs);
    const float2* p1 = (const float2*)(W_hh + (size_t)R1 * HID + 64 * cs);
#pragma unroll
    for (int k = 0; k < 32; ++k) {
      float2 a = p0[k], c = p1[k];
      w0[k] = pack_h2(a.x, a.y);
      w1[k] = pack_h2(c.x, c.y);
    }
  }
  // ---- one-time: x0 column, y partials, gacc ----
  for (int i = tid; i < T_STEPS; i += BLK_THREADS) {
    x0_lds[i] = x0[i * BATCH + b];
    ylds[i] = 0.f;
  }
  if (tid < 256) { gacc[0][tid] = 0.f; gacc[1][tid] = 0.f; }

  // ---- activation-lane constants (lanes 0..63 of wave 0) ----
  float c_state = 0.f;
  float wih_[4] = {0.f, 0.f, 0.f, 0.f}, bs_[4] = {0.f, 0.f, 0.f, 0.f};
  float wlin_u = 0.f, blin = 0.f;
  if (tid < 64) {
#pragma unroll
    for (int j = 0; j < 4; ++j) {
      int R = j * HID + u0 + tid;
      wih_[j] = W_ih[R];
      bs_[j] = b_ih[R] + b_hh[R];
    }
    wlin_u = W_lin[u0 + tid];
    blin = b_lin[0];
  }

  // ---- pointers ----
  uint32_t* tags_b = tags + b * 8;
  uint32_t* hrec[2] = { h_ex + (size_t)b * BSLOT_DW,
                        h_ex + SLOT_DW + (size_t)b * BSLOT_DW };
  uint32_t* pub01[2] = { hrec[0] + 32 * g, hrec[1] + 32 * g };

  __syncthreads();

  int dead = 0;
  for (int t = 0; t < T_STEPS; ++t) {
    const int sl = t & 1, ns = sl ^ 1;

    // ---- wave 15: poll 8 tags, then fetch whole batch record -> LDS ----
    if (wv == 15) {
      {
        int guard = 0;
        for (;;) {
          bool ok = true;
          if (l < 8) {
            uint32_t tg = __hip_atomic_load(&tags_b[l], __ATOMIC_RELAXED,
                                            __HIP_MEMORY_SCOPE_AGENT);
            ok = ((int)tg >= t);
          }
          if (__all(ok)) break;
          if (dead || ++guard > (1 << 17)) { dead = 1; break; }  // anti-hang
        }
      }
      // fetch: 64 lanes x 2 qwords = 256 dwords (1 KB), one parallel RT.
      // Issued strictly AFTER the tag check passed -> L2 serves it after it
      // served the (fresh) tag -> data is >= step t (release on producer).
      const uint64_t* src = (const uint64_t*)hrec[sl];
      uint64_t q0 = __hip_atomic_load(&src[l], __ATOMIC_RELAXED,
                                      __HIP_MEMORY_SCOPE_AGENT);
      uint64_t q1 = __hip_atomic_load(&src[l + 64], __ATOMIC_RELAXED,
                                      __HIP_MEMORY_SCOPE_AGENT);
      uint64_t* dst = (uint64_t*)h_lds[sl];
      dst[l] = q0;
      dst[l + 64] = q1;
    }
    __syncthreads();   // barrier #1: h_lds[sl] ready (replaces 16-wave poll)

    // ---- matvec: 2 rows x 64 cols per lane; h via broadcast ds_read_b128 ----
    const u32x4* hs4 = (const u32x4*)&h_lds[sl][32 * cs];
    float acc0a = 0.f, acc0b = 0.f, acc1a = 0.f, acc1b = 0.f;
#pragma unroll
    for (int k = 0; k < 8; ++k) {
      u32x4 hv = hs4[k];
      acc0a = fdot2(w0[4 * k + 0], hv[0], acc0a);
      acc1a = fdot2(w1[4 * k + 0], hv[0], acc1a);
      acc0b = fdot2(w0[4 * k + 1], hv[1], acc0b);
      acc1b = fdot2(w1[4 * k + 1], hv[1], acc1b);
      acc0a = fdot2(w0[4 * k + 2], hv[2], acc0a);
      acc1a = fdot2(w1[4 * k + 2], hv[2], acc1a);
      acc0b = fdot2(w0[4 * k + 3], hv[3], acc0b);
      acc1b = fdot2(w1[4 * k + 3], hv[3], acc1b);
    }
    atomicAdd(&gacc[sl][128 * rg + l], acc0a + acc0b);      // conflict-free
    atomicAdd(&gacc[sl][128 * rg + 64 + l], acc1a + acc1b);
    __syncthreads();   // barrier #2: gacc complete

    // ---- activations + publish (wave 0, 64 lanes = 64 owned units) ----
    if (tid < 64) {
      const float xv = x0_lds[t];
      float gi = gacc[sl][tid]       + xv * wih_[0] + bs_[0];
      float gf = gacc[sl][tid + 64]  + xv * wih_[1] + bs_[1];
      float gg = gacc[sl][tid + 128] + xv * wih_[2] + bs_[2];
      float go = gacc[sl][tid + 192] + xv * wih_[3] + bs_[3];
      float si = sigf(gi), sf = sigf(gf), tg_ = tanh_fast(gg), so = sigf(go);
      c_state = sf * c_state + si * tg_;
      float h = so * tanh_fast(c_state);

      // publish data: even lanes store 32 packed dwords (coalesced) ...
      float hn = __shfl_down(h, 1, 64);
      if ((tid & 1) == 0) pub01[ns][tid >> 1] = pack_h2(h, hn);
      // ... wave-level drain (covers ALL lanes' stores), then release tag.
      asm volatile("s_waitcnt vmcnt(0)" ::: "memory");
      if (tid == 0)
        __hip_atomic_store(&tags_b[g], (uint32_t)(t + 1), __ATOMIC_RELEASE,
                           __HIP_MEMORY_SCOPE_AGENT);

      // recycle gacc[sl] for step t+2 (safe: next barrier#1 orders it)
      gacc[sl][tid] = 0.f;
      gacc[sl][tid + 64] = 0.f;
      gacc[sl][tid + 128] = 0.f;
      gacc[sl][tid + 192] = 0.f;

      // y partial (off critical path): fold 64 units -> ylds[t]
      float p = wlin_u * h;
#pragma unroll
      for (int m = 32; m >= 1; m >>= 1) p += __shfl_xor(p, m, 64);
      if (tid == 0) ylds[t] = p;
    }
  }

  // ---- drain: block partials -> global y (g==0 adds bias + residual) ----
  __syncthreads();
  for (int i = tid; i < T_STEPS; i += BLK_THREADS) {
    float val = ylds[i];
    if (g == 0) val += blin + x0_lds[i];
    unsafeAtomicAdd(&y[i * BATCH + b], val);
  }
}

extern "C" void kernel_launch(void* const* d_in, const int* in_sizes, int n_in,
                              void* d_out, int out_size, void* d_ws, size_t ws_size,
                              hipStream_t stream) {
  const float* x0    = (const float*)d_in[0];
  const float* W_ih  = (const float*)d_in[1];
  const float* W_hh  = (const float*)d_in[2];
  const float* b_ih  = (const float*)d_in[3];
  const float* b_hh  = (const float*)d_in[4];
  const float* W_lin = (const float*)d_in[5];
  const float* b_lin = (const float*)d_in[6];
  float* y = (float*)d_out;

  uint32_t* h_ex = (uint32_t*)d_ws;                    // 2 x 32 KB slots
  uint32_t* tags = h_ex + 2 * SLOT_DW;                 // 1 KB
  int* claim     = (int*)(tags + BATCH * 8);           // 512 B
  const size_t init_bytes = (size_t)(2 * SLOT_DW + BATCH * 8) * sizeof(uint32_t)
                            + 8 * 16 * sizeof(int);

  // memset 0: slot-0 h = 0 (== h0), tags = 0 ("h_0 available"), claim = 0
  (void)hipMemsetAsync(d_ws, 0, init_bytes, stream);
  (void)hipMemsetAsync(d_out, 0, (size_t)out_size * sizeof(float), stream);

  hipLaunchKernelGGL(lstm_vecagent, dim3(NBLOCKS), dim3(BLK_THREADS), 0, stream,
                     x0, W_ih, W_hh, b_ih, b_hh, W_lin, b_lin, y, h_ex, tags,
                     claim);
}